// Round 1
// baseline (1982.741 us; speedup 1.0000x reference)
//
#include <hip/hip_runtime.h>
#include <hip/hip_bf16.h>
#include <stdint.h>

// ---------- types / helpers ----------
typedef short bf16x8 __attribute__((ext_vector_type(8)));
typedef float f32x4 __attribute__((ext_vector_type(4)));

typedef const __attribute__((address_space(1))) unsigned int glob_u32;
typedef __attribute__((address_space(3))) unsigned int lds_u32;

__device__ __forceinline__ void gl_lds16(const void* g, void* s) {
  // 16B global->LDS direct copy; LDS dest = wave-uniform base + lane*16
  __builtin_amdgcn_global_load_lds((glob_u32*)g, (lds_u32*)s, 16, 0, 0);
}

__device__ __forceinline__ unsigned short f2bf(float f) {
  __hip_bfloat16 h = __float2bfloat16(f);
  return __builtin_bit_cast(unsigned short, h);
}
__device__ __forceinline__ float bf2f(unsigned short u) {
  __hip_bfloat16 h = __builtin_bit_cast(__hip_bfloat16, u);
  return __bfloat162float(h);
}

// ---------- split fp32 -> bf16 hi/lo ----------
__global__ void split_hl(const float* __restrict__ src,
                         unsigned short* __restrict__ hi,
                         unsigned short* __restrict__ lo, int n4) {
  int i = blockIdx.x * blockDim.x + threadIdx.x;
  if (i >= n4) return;
  float4 v = reinterpret_cast<const float4*>(src)[i];
  ushort4 h, l;
  h.x = f2bf(v.x); l.x = f2bf(v.x - bf2f(h.x));
  h.y = f2bf(v.y); l.y = f2bf(v.y - bf2f(h.y));
  h.z = f2bf(v.z); l.z = f2bf(v.z - bf2f(h.z));
  h.w = f2bf(v.w); l.w = f2bf(v.w - bf2f(h.w));
  reinterpret_cast<ushort4*>(hi)[i] = h;
  reinterpret_cast<ushort4*>(lo)[i] = l;
}

// ---------- embedding gather + split ----------
__global__ void gather_split(const int* __restrict__ x, const float* __restrict__ emb,
                             unsigned short* __restrict__ hi,
                             unsigned short* __restrict__ lo) {
  int i = blockIdx.x * 256 + threadIdx.x;  // [0, 4096*128)
  int m = i >> 7, k4 = i & 127;
  long row = x[m];
  float4 v = reinterpret_cast<const float4*>(emb + row * 512)[k4];
  ushort4 h, l;
  h.x = f2bf(v.x); l.x = f2bf(v.x - bf2f(h.x));
  h.y = f2bf(v.y); l.y = f2bf(v.y - bf2f(h.y));
  h.z = f2bf(v.z); l.z = f2bf(v.z - bf2f(h.z));
  h.w = f2bf(v.w); l.w = f2bf(v.w - bf2f(h.w));
  reinterpret_cast<ushort4*>(hi)[m * 128 + k4] = h;
  reinterpret_cast<ushort4*>(lo)[m * 128 + k4] = l;
}

// ---------- split-bf16 GEMM: C[M,N] = A[M,K] @ B[N,K]^T + bias ----------
// M = 4096, K = 512 fixed. 128x128 tile, 4 waves, 3-product hi/lo MFMA.
__global__ __launch_bounds__(256) void gemm_split(
    const unsigned short* __restrict__ Ahi, const unsigned short* __restrict__ Alo,
    const unsigned short* __restrict__ Bhi, const unsigned short* __restrict__ Blo,
    float* __restrict__ C, const float* __restrict__ bias1,
    const float* __restrict__ bias2, int N, int mtiles) {
  __shared__ unsigned short lds[4][128 * 64];  // Ahi, Alo, Bhi, Blo tiles (64 KiB)
  int bid = blockIdx.x;
  int mt = bid % mtiles, nt = bid / mtiles;  // m-inner: blocks sharing B panel run together
  int m0 = mt * 128, n0 = nt * 128;
  int tid = threadIdx.x, l = tid & 63, w = tid >> 6;
  int wm = (w & 1) * 64, wn = (w >> 1) * 64;

  f32x4 acc[4][4];
#pragma unroll
  for (int a = 0; a < 4; ++a)
#pragma unroll
    for (int b = 0; b < 4; ++b) acc[a][b] = f32x4{0.f, 0.f, 0.f, 0.f};

  const unsigned short* srcs[4] = {Ahi, Alo, Bhi, Blo};

  for (int kc = 0; kc < 8; ++kc) {   // K=512 in chunks of 64
    __syncthreads();                  // protect LDS WAR from previous MFMA phase
#pragma unroll
    for (int tile = 0; tile < 4; ++tile) {
      const unsigned short* src = srcs[tile];
      int rbase = (tile < 2) ? m0 : n0;
#pragma unroll
      for (int i = 0; i < 4; ++i) {
        int G = (i * 4 + w) * 64 + l;  // granule 0..1023 (16B each)
        int r = G >> 3, g = G & 7;
        int row = rbase + r;
        if (tile >= 2 && row >= N) row = n0;  // clamp ragged N tile (garbage discarded)
        // XOR-swizzle applied on the per-lane GLOBAL address; LDS stays linear
        long gb = (long)row * 1024 + kc * 128 + ((g * 16) ^ ((r & 7) << 4));
        gl_lds16((const char*)src + gb, (char*)(&lds[tile][0]) + (i * 4 + w) * 1024);
      }
    }
    __syncthreads();  // drains vmcnt(0): staged data visible

    const char* ldsb = (const char*)&lds[0][0];
#pragma unroll
    for (int ks = 0; ks < 2; ++ks) {
      bf16x8 ah[4], al[4], bh[4], bl[4];
      int biw = ks * 64 + ((l >> 4) * 16);
#pragma unroll
      for (int fm = 0; fm < 4; ++fm) {
        int row = wm + fm * 16 + (l & 15);
        int off = row * 128 + (biw ^ ((row & 7) << 4));
        ah[fm] = *reinterpret_cast<const bf16x8*>(ldsb + off);
        al[fm] = *reinterpret_cast<const bf16x8*>(ldsb + 16384 + off);
      }
#pragma unroll
      for (int fn = 0; fn < 4; ++fn) {
        int row = wn + fn * 16 + (l & 15);
        int off = row * 128 + (biw ^ ((row & 7) << 4));
        bh[fn] = *reinterpret_cast<const bf16x8*>(ldsb + 32768 + off);
        bl[fn] = *reinterpret_cast<const bf16x8*>(ldsb + 49152 + off);
      }
#pragma unroll
      for (int fm = 0; fm < 4; ++fm)
#pragma unroll
        for (int fn = 0; fn < 4; ++fn) {
          acc[fm][fn] = __builtin_amdgcn_mfma_f32_16x16x32_bf16(ah[fm], bh[fn], acc[fm][fn], 0, 0, 0);
          acc[fm][fn] = __builtin_amdgcn_mfma_f32_16x16x32_bf16(ah[fm], bl[fn], acc[fm][fn], 0, 0, 0);
          acc[fm][fn] = __builtin_amdgcn_mfma_f32_16x16x32_bf16(al[fm], bh[fn], acc[fm][fn], 0, 0, 0);
        }
    }
  }

  // epilogue: C/D layout col=lane&15, row=(lane>>4)*4+j
#pragma unroll
  for (int fn = 0; fn < 4; ++fn) {
    int n = n0 + wn + fn * 16 + (l & 15);
    if (n < N) {
      float bs = bias1[n];
      if (bias2) bs += bias2[n];
#pragma unroll
      for (int fm = 0; fm < 4; ++fm) {
        int mb = m0 + wm + fm * 16 + (l >> 4) * 4;
#pragma unroll
        for (int j = 0; j < 4; ++j)
          C[(long)(mb + j) * N + n] = acc[fm][fn][j] + bs;
      }
    }
  }
}

// ---------- persistent LSTM: 256 blocks, batch = bid&7, slice = bid>>3 ----------
// h published via sentinel-poll (lstm_f32 pre-set to 0xFFFFFFFF = NaN pattern).
__global__ __launch_bounds__(256) void lstm_persistent(
    const float* __restrict__ xproj,   // [8][512][2048] (b_ih+b_hh already folded in)
    const float* __restrict__ whh,     // [2048][512]
    float* lstm_f32,                   // [8][512][512] sentinel-initialized
    unsigned short* __restrict__ lstm_hi, unsigned short* __restrict__ lstm_lo) {
  int bid = blockIdx.x;
  int batch = bid & 7, slice = bid >> 3;  // siblings of a batch land on one XCD (round-robin)
  int tid = threadIdx.x, l = tid & 63, w = tid >> 6;
  int g = l >> 4, e = l & 15;
  long R = (long)g * 512 + slice * 16 + e;  // gate row in [0,2048)

  __shared__ float h_s[512];
  __shared__ float part_s[4][64];
  __shared__ float c_s[16];
  if (tid < 16) c_s[tid] = 0.f;

  // W slice resident in registers: lane -> row R, wave -> k chunk [w*128, w*128+128)
  float wreg[128];
  const float* wp = whh + R * 512 + w * 128;
#pragma unroll
  for (int jj = 0; jj < 32; ++jj) {
    float4 v = reinterpret_cast<const float4*>(wp)[jj];
    wreg[jj * 4 + 0] = v.x; wreg[jj * 4 + 1] = v.y;
    wreg[jj * 4 + 2] = v.z; wreg[jj * 4 + 3] = v.w;
  }
  __syncthreads();

  for (int t = 0; t < 512; ++t) {
    // prefetch xproj gate inputs early (latency hides under the poll)
    float xp0 = 0.f, xp1 = 0.f, xp2 = 0.f, xp3 = 0.f;
    if (tid < 16) {
      const float* xr = xproj + ((long)batch * 512 + t) * 2048 + slice * 16 + tid;
      xp0 = xr[0]; xp1 = xr[512]; xp2 = xr[1024]; xp3 = xr[1536];
    }

    float acc = 0.f;
    if (t > 0) {
      // wave w needs h[w*128 .. w*128+128): each lane polls 2 words
      const unsigned int* src = reinterpret_cast<const unsigned int*>(
          lstm_f32 + ((long)batch * 512 + (t - 1)) * 512);
      int i0 = w * 128 + l;
      unsigned int u0, u1;
      do { u0 = __hip_atomic_load(src + i0, __ATOMIC_RELAXED, __HIP_MEMORY_SCOPE_AGENT); } while (u0 == 0xFFFFFFFFu);
      do { u1 = __hip_atomic_load(src + i0 + 64, __ATOMIC_RELAXED, __HIP_MEMORY_SCOPE_AGENT); } while (u1 == 0xFFFFFFFFu);
      h_s[i0] = __builtin_bit_cast(float, u0);
      h_s[i0 + 64] = __builtin_bit_cast(float, u1);
      asm volatile("s_waitcnt lgkmcnt(0)" ::: "memory");  // cross-lane LDS visibility in-wave
      __builtin_amdgcn_sched_barrier(0);
#pragma unroll
      for (int jj = 0; jj < 32; ++jj) {
        float4 h4 = *reinterpret_cast<const float4*>(&h_s[w * 128 + jj * 4]);
        acc = fmaf(wreg[jj * 4 + 0], h4.x, acc);
        acc = fmaf(wreg[jj * 4 + 1], h4.y, acc);
        acc = fmaf(wreg[jj * 4 + 2], h4.z, acc);
        acc = fmaf(wreg[jj * 4 + 3], h4.w, acc);
      }
    }
    part_s[w][l] = acc;
    __syncthreads();

    if (tid < 16) {
      float gi = xp0, gf = xp1, gG = xp2, go = xp3;
#pragma unroll
      for (int ww = 0; ww < 4; ++ww) {
        gi += part_s[ww][tid];
        gf += part_s[ww][16 + tid];
        gG += part_s[ww][32 + tid];
        go += part_s[ww][48 + tid];
      }
      float iv = 1.f / (1.f + expf(-gi));
      float fv = 1.f / (1.f + expf(-gf));
      float gv = tanhf(gG);
      float ov = 1.f / (1.f + expf(-go));
      float c = fv * c_s[tid] + iv * gv;
      float h = ov * tanhf(c);
      c_s[tid] = c;
      long oidx = ((long)batch * 512 + t) * 512 + slice * 16 + tid;
      __hip_atomic_store(reinterpret_cast<unsigned int*>(lstm_f32) + oidx,
                         __builtin_bit_cast(unsigned int, h),
                         __ATOMIC_RELAXED, __HIP_MEMORY_SCOPE_AGENT);
      unsigned short hb = f2bf(h);
      lstm_hi[oidx] = hb;
      lstm_lo[oidx] = f2bf(h - bf2f(hb));
    }
    __syncthreads();  // protect part_s / ensure publish before next iteration
  }
}

// ---------- launch ----------
extern "C" void kernel_launch(void* const* d_in, const int* in_sizes, int n_in,
                              void* d_out, int out_size, void* d_ws, size_t ws_size,
                              hipStream_t stream) {
  const int*   x         = (const int*)d_in[0];
  const float* embedding = (const float*)d_in[2];
  const float* w_ih      = (const float*)d_in[3];
  const float* w_hh      = (const float*)d_in[4];
  const float* b_ih      = (const float*)d_in[5];
  const float* b_hh      = (const float*)d_in[6];
  const float* dec_w     = (const float*)d_in[7];
  const float* dec_b     = (const float*)d_in[8];

  char* ws = (char*)d_ws;
  float* xproj = (float*)ws;                      ws += (size_t)4096 * 2048 * 4;
  float* lstmf = (float*)ws;                      ws += (size_t)4096 * 512 * 4;
  unsigned short* lstm_hi = (unsigned short*)ws;  ws += (size_t)4096 * 512 * 2;
  unsigned short* lstm_lo = (unsigned short*)ws;  ws += (size_t)4096 * 512 * 2;
  unsigned short* emb_hi  = (unsigned short*)ws;  ws += (size_t)4096 * 512 * 2;
  unsigned short* emb_lo  = (unsigned short*)ws;  ws += (size_t)4096 * 512 * 2;
  unsigned short* wih_hi  = (unsigned short*)ws;  ws += (size_t)2048 * 512 * 2;
  unsigned short* wih_lo  = (unsigned short*)ws;  ws += (size_t)2048 * 512 * 2;
  unsigned short* dw_hi   = (unsigned short*)ws;  ws += (size_t)50000 * 512 * 2;
  unsigned short* dw_lo   = (unsigned short*)ws;  ws += (size_t)50000 * 512 * 2;

  // reset h sentinel (poll buffer) every call — determinism across replays
  hipMemsetAsync(lstmf, 0xFF, (size_t)4096 * 512 * 4, stream);

  split_hl<<<1024, 256, 0, stream>>>(w_ih, wih_hi, wih_lo, 2048 * 512 / 4);
  split_hl<<<25000, 256, 0, stream>>>(dec_w, dw_hi, dw_lo, 50000 * 512 / 4);
  gather_split<<<2048, 256, 0, stream>>>(x, embedding, emb_hi, emb_lo);

  // xproj = embed @ w_ih^T + (b_ih + b_hh)
  gemm_split<<<32 * 16, 256, 0, stream>>>(emb_hi, emb_lo, wih_hi, wih_lo, xproj,
                                          b_ih, b_hh, 2048, 32);

  {
    void* args[] = {(void*)&xproj, (void*)&w_hh, (void*)&lstmf,
                    (void*)&lstm_hi, (void*)&lstm_lo};
    hipLaunchCooperativeKernel((void*)lstm_persistent, dim3(256), dim3(256), args, 0, stream);
  }

  // y = lstm_out @ dec_w^T + dec_b
  gemm_split<<<32 * 391, 256, 0, stream>>>(lstm_hi, lstm_lo, dw_hi, dw_lo,
                                           (float*)d_out, dec_b, (const float*)nullptr,
                                           50000, 32);
}

// Round 2
// 1721.967 us; speedup vs baseline: 1.1514x; 1.1514x over previous
//
#include <hip/hip_runtime.h>
#include <hip/hip_bf16.h>
#include <stdint.h>

// ---------- types / helpers ----------
typedef short bf16x8 __attribute__((ext_vector_type(8)));
typedef float f32x4 __attribute__((ext_vector_type(4)));

typedef const __attribute__((address_space(1))) unsigned int glob_u32;
typedef __attribute__((address_space(3))) unsigned int lds_u32;

__device__ __forceinline__ void gl_lds16(const void* g, void* s) {
  // 16B global->LDS direct copy; LDS dest = wave-uniform base + lane*16
  __builtin_amdgcn_global_load_lds((glob_u32*)g, (lds_u32*)s, 16, 0, 0);
}

__device__ __forceinline__ unsigned short f2bf(float f) {
  __hip_bfloat16 h = __float2bfloat16(f);
  return __builtin_bit_cast(unsigned short, h);
}
__device__ __forceinline__ float bf2f(unsigned short u) {
  __hip_bfloat16 h = __builtin_bit_cast(__hip_bfloat16, u);
  return __bfloat162float(h);
}

__device__ __forceinline__ float sigm_fast(float x) {
  float e = __expf(-x);                       // v_exp_f32 path
  return __builtin_amdgcn_rcpf(1.f + e);      // rel err ~1e-5, fine vs 9.8e-3 budget
}
__device__ __forceinline__ float tanh_fast(float x) {
  float e = __expf(2.f * x);                  // inf-safe: rcp(inf)=0 -> 1
  return 1.f - 2.f * __builtin_amdgcn_rcpf(e + 1.f);
}

// ---------- split fp32 -> bf16 hi/lo ----------
__global__ void split_hl(const float* __restrict__ src,
                         unsigned short* __restrict__ hi,
                         unsigned short* __restrict__ lo, int n4) {
  int i = blockIdx.x * blockDim.x + threadIdx.x;
  if (i >= n4) return;
  float4 v = reinterpret_cast<const float4*>(src)[i];
  ushort4 h, l;
  h.x = f2bf(v.x); l.x = f2bf(v.x - bf2f(h.x));
  h.y = f2bf(v.y); l.y = f2bf(v.y - bf2f(h.y));
  h.z = f2bf(v.z); l.z = f2bf(v.z - bf2f(h.z));
  h.w = f2bf(v.w); l.w = f2bf(v.w - bf2f(h.w));
  reinterpret_cast<ushort4*>(hi)[i] = h;
  reinterpret_cast<ushort4*>(lo)[i] = l;
}

// ---------- embedding gather + split ----------
__global__ void gather_split(const int* __restrict__ x, const float* __restrict__ emb,
                             unsigned short* __restrict__ hi,
                             unsigned short* __restrict__ lo) {
  int i = blockIdx.x * 256 + threadIdx.x;  // [0, 4096*128)
  int m = i >> 7, k4 = i & 127;
  long row = x[m];
  float4 v = reinterpret_cast<const float4*>(emb + row * 512)[k4];
  ushort4 h, l;
  h.x = f2bf(v.x); l.x = f2bf(v.x - bf2f(h.x));
  h.y = f2bf(v.y); l.y = f2bf(v.y - bf2f(h.y));
  h.z = f2bf(v.z); l.z = f2bf(v.z - bf2f(h.z));
  h.w = f2bf(v.w); l.w = f2bf(v.w - bf2f(h.w));
  reinterpret_cast<ushort4*>(hi)[m * 128 + k4] = h;
  reinterpret_cast<ushort4*>(lo)[m * 128 + k4] = l;
}

// ---------- split-bf16 GEMM: C[M,N] = A[M,K] @ B[N,K]^T + bias ----------
// M = 4096, K = 512 fixed. 128x128 tile, 4 waves, 3-product hi/lo MFMA.
__global__ __launch_bounds__(256) void gemm_split(
    const unsigned short* __restrict__ Ahi, const unsigned short* __restrict__ Alo,
    const unsigned short* __restrict__ Bhi, const unsigned short* __restrict__ Blo,
    float* __restrict__ C, const float* __restrict__ bias1,
    const float* __restrict__ bias2, int N, int mtiles) {
  __shared__ unsigned short lds[4][128 * 64];  // Ahi, Alo, Bhi, Blo tiles (64 KiB)
  // bijective XCD-chunked swizzle (gridDim.x % 8 == 0): each XCD owns a
  // contiguous wid range -> contiguous n-panels -> B panel stays in its L2.
  int nwg = gridDim.x;
  int wid = (blockIdx.x & 7) * (nwg >> 3) + (blockIdx.x >> 3);
  int mt = wid % mtiles, nt = wid / mtiles;
  int m0 = mt * 128, n0 = nt * 128;
  int tid = threadIdx.x, l = tid & 63, w = tid >> 6;
  int wm = (w & 1) * 64, wn = (w >> 1) * 64;

  f32x4 acc[4][4];
#pragma unroll
  for (int a = 0; a < 4; ++a)
#pragma unroll
    for (int b = 0; b < 4; ++b) acc[a][b] = f32x4{0.f, 0.f, 0.f, 0.f};

  const unsigned short* srcs[4] = {Ahi, Alo, Bhi, Blo};

  for (int kc = 0; kc < 8; ++kc) {   // K=512 in chunks of 64
    __syncthreads();                  // protect LDS WAR from previous MFMA phase
#pragma unroll
    for (int tile = 0; tile < 4; ++tile) {
      const unsigned short* src = srcs[tile];
      int rbase = (tile < 2) ? m0 : n0;
#pragma unroll
      for (int i = 0; i < 4; ++i) {
        int G = (i * 4 + w) * 64 + l;  // granule 0..1023 (16B each)
        int r = G >> 3, g = G & 7;
        int row = rbase + r;
        if (tile >= 2 && row >= N) row = n0;  // clamp ragged N tile (garbage discarded)
        // XOR-swizzle applied on the per-lane GLOBAL address; LDS stays linear
        long gb = (long)row * 1024 + kc * 128 + ((g * 16) ^ ((r & 7) << 4));
        gl_lds16((const char*)src + gb, (char*)(&lds[tile][0]) + (i * 4 + w) * 1024);
      }
    }
    __syncthreads();  // drains vmcnt(0): staged data visible

    const char* ldsb = (const char*)&lds[0][0];
#pragma unroll
    for (int ks = 0; ks < 2; ++ks) {
      bf16x8 ah[4], al[4], bh[4], bl[4];
      int biw = ks * 64 + ((l >> 4) * 16);
#pragma unroll
      for (int fm = 0; fm < 4; ++fm) {
        int row = wm + fm * 16 + (l & 15);
        int off = row * 128 + (biw ^ ((row & 7) << 4));
        ah[fm] = *reinterpret_cast<const bf16x8*>(ldsb + off);
        al[fm] = *reinterpret_cast<const bf16x8*>(ldsb + 16384 + off);
      }
#pragma unroll
      for (int fn = 0; fn < 4; ++fn) {
        int row = wn + fn * 16 + (l & 15);
        int off = row * 128 + (biw ^ ((row & 7) << 4));
        bh[fn] = *reinterpret_cast<const bf16x8*>(ldsb + 32768 + off);
        bl[fn] = *reinterpret_cast<const bf16x8*>(ldsb + 49152 + off);
      }
#pragma unroll
      for (int fm = 0; fm < 4; ++fm)
#pragma unroll
        for (int fn = 0; fn < 4; ++fn) {
          acc[fm][fn] = __builtin_amdgcn_mfma_f32_16x16x32_bf16(ah[fm], bh[fn], acc[fm][fn], 0, 0, 0);
          acc[fm][fn] = __builtin_amdgcn_mfma_f32_16x16x32_bf16(ah[fm], bl[fn], acc[fm][fn], 0, 0, 0);
          acc[fm][fn] = __builtin_amdgcn_mfma_f32_16x16x32_bf16(al[fm], bh[fn], acc[fm][fn], 0, 0, 0);
        }
    }
  }

  // epilogue: C/D layout col=lane&15, row=(lane>>4)*4+j
#pragma unroll
  for (int fn = 0; fn < 4; ++fn) {
    int n = n0 + wn + fn * 16 + (l & 15);
    if (n < N) {
      float bs = bias1[n];
      if (bias2) bs += bias2[n];
#pragma unroll
      for (int fm = 0; fm < 4; ++fm) {
        int mb = m0 + wm + fm * 16 + (l >> 4) * 4;
#pragma unroll
        for (int j = 0; j < 4; ++j)
          C[(long)(mb + j) * N + n] = acc[fm][fn][j] + bs;
      }
    }
  }
}

// ---------- persistent LSTM: 256 blocks, batch = bid&7, slice = bid>>3 ----------
// h published via sentinel-poll (lstm_f32 pre-set to 0xFFFFFFFF = NaN pattern).
// w_hh slice PINNED in VGPRs (128 f32/lane) via asm keep-alive.
__global__ __launch_bounds__(256, 1) void lstm_persistent(
    const float* __restrict__ xproj,   // [8][512][2048] (b_ih+b_hh folded in)
    const float* __restrict__ whh,     // [2048][512]
    float* lstm_f32,                   // [8][512][512] sentinel-initialized
    unsigned short* __restrict__ lstm_hi, unsigned short* __restrict__ lstm_lo) {
  int bid = blockIdx.x;
  int batch = bid & 7, slice = bid >> 3;
  int tid = threadIdx.x, l = tid & 63, w = tid >> 6;
  int g = l >> 4, e = l & 15;
  long R = (long)g * 512 + slice * 16 + e;  // gate row in [0,2048)

  __shared__ float h_s[512];
  __shared__ float part_s[4][64];

  // ---- load W slice and PIN it in VGPRs ----
  float wr[128];
  {
    const float4* wp = reinterpret_cast<const float4*>(whh + R * 512) + w * 32;
#pragma unroll
    for (int jj = 0; jj < 32; ++jj) {
      float4 v = wp[jj];
      wr[jj * 4 + 0] = v.x; wr[jj * 4 + 1] = v.y;
      wr[jj * 4 + 2] = v.z; wr[jj * 4 + 3] = v.w;
    }
  }
#pragma unroll
  for (int jj = 0; jj < 128; jj += 4)
    asm volatile("" : "+v"(wr[jj]), "+v"(wr[jj + 1]), "+v"(wr[jj + 2]), "+v"(wr[jj + 3]));

  const float* xbase = xproj + (long)batch * 512 * 2048 + g * 512 + slice * 16 + e;
  float* hrow_base = lstm_f32 + (long)batch * 512 * 512;
  float c_reg = 0.f;
  __syncthreads();

  for (int t = 0; t < 512; ++t) {
    // xproj prefetch (wave 0 only) — hides HBM latency under the poll
    float xp = 0.f;
    if (w == 0) xp = xbase[(long)t * 2048];

    float a0 = 0.f, a1 = 0.f, a2 = 0.f, a3 = 0.f;
    if (t > 0) {
      // wave w polls its k-range h[w*128 .. +128): one 8B atomic per lane
      const unsigned long long* src = reinterpret_cast<const unsigned long long*>(
          hrow_base + (long)(t - 1) * 512 + w * 128);
      unsigned long long u;
      for (;;) {
        u = __hip_atomic_load(src + l, __ATOMIC_RELAXED, __HIP_MEMORY_SCOPE_AGENT);
        if ((unsigned)u != 0xFFFFFFFFu && (unsigned)(u >> 32) != 0xFFFFFFFFu) break;
      }
      float2 hf;
      hf.x = __builtin_bit_cast(float, (unsigned)u);
      hf.y = __builtin_bit_cast(float, (unsigned)(u >> 32));
      *reinterpret_cast<float2*>(&h_s[w * 128 + 2 * l]) = hf;
      asm volatile("s_waitcnt lgkmcnt(0)" ::: "memory");
      __builtin_amdgcn_sched_barrier(0);
#pragma unroll
      for (int jj = 0; jj < 32; ++jj) {
        float4 h4 = *reinterpret_cast<const float4*>(&h_s[w * 128 + jj * 4]);
        a0 = fmaf(wr[jj * 4 + 0], h4.x, a0);
        a1 = fmaf(wr[jj * 4 + 1], h4.y, a1);
        a2 = fmaf(wr[jj * 4 + 2], h4.z, a2);
        a3 = fmaf(wr[jj * 4 + 3], h4.w, a3);
      }
    }
    part_s[w][l] = (a0 + a1) + (a2 + a3);
    __syncthreads();

    if (w == 0) {
      // 64 lanes: lane l = gate g, elem e. One transcendental per lane.
      float sum = xp + part_s[0][l] + part_s[1][l] + part_s[2][l] + part_s[3][l];
      float val = (g == 2) ? tanh_fast(sum) : sigm_fast(sum);
      float vf = __shfl(val, e + 16);   // f gate
      float vg = __shfl(val, e + 32);   // g gate
      float vo = __shfl(val, e + 48);   // o gate
      if (l < 16) {
        float c = vf * c_reg + val * vg;   // val = i for lanes 0..15
        c_reg = c;
        float h = vo * tanh_fast(c);
        long oidx = ((long)batch * 512 + t) * 512 + slice * 16 + l;
        __hip_atomic_store(reinterpret_cast<unsigned int*>(lstm_f32) + oidx,
                           __builtin_bit_cast(unsigned int, h),
                           __ATOMIC_RELAXED, __HIP_MEMORY_SCOPE_AGENT);
        unsigned short hb = f2bf(h);
        lstm_hi[oidx] = hb;
        lstm_lo[oidx] = f2bf(h - bf2f(hb));
      }
    }
    __syncthreads();  // release part_s for next step
  }
}

// ---------- launch ----------
extern "C" void kernel_launch(void* const* d_in, const int* in_sizes, int n_in,
                              void* d_out, int out_size, void* d_ws, size_t ws_size,
                              hipStream_t stream) {
  const int*   x         = (const int*)d_in[0];
  const float* embedding = (const float*)d_in[2];
  const float* w_ih      = (const float*)d_in[3];
  const float* w_hh      = (const float*)d_in[4];
  const float* b_ih      = (const float*)d_in[5];
  const float* b_hh      = (const float*)d_in[6];
  const float* dec_w     = (const float*)d_in[7];
  const float* dec_b     = (const float*)d_in[8];

  char* ws = (char*)d_ws;
  float* xproj = (float*)ws;                      ws += (size_t)4096 * 2048 * 4;
  float* lstmf = (float*)ws;                      ws += (size_t)4096 * 512 * 4;
  unsigned short* lstm_hi = (unsigned short*)ws;  ws += (size_t)4096 * 512 * 2;
  unsigned short* lstm_lo = (unsigned short*)ws;  ws += (size_t)4096 * 512 * 2;
  unsigned short* emb_hi  = (unsigned short*)ws;  ws += (size_t)4096 * 512 * 2;
  unsigned short* emb_lo  = (unsigned short*)ws;  ws += (size_t)4096 * 512 * 2;
  unsigned short* wih_hi  = (unsigned short*)ws;  ws += (size_t)2048 * 512 * 2;
  unsigned short* wih_lo  = (unsigned short*)ws;  ws += (size_t)2048 * 512 * 2;
  unsigned short* dw_hi   = (unsigned short*)ws;  ws += (size_t)50000 * 512 * 2;
  unsigned short* dw_lo   = (unsigned short*)ws;  ws += (size_t)50000 * 512 * 2;

  // reset h sentinel (poll buffer) every call — determinism across replays
  hipMemsetAsync(lstmf, 0xFF, (size_t)4096 * 512 * 4, stream);

  split_hl<<<1024, 256, 0, stream>>>(w_ih, wih_hi, wih_lo, 2048 * 512 / 4);
  split_hl<<<25000, 256, 0, stream>>>(dec_w, dw_hi, dw_lo, 50000 * 512 / 4);
  gather_split<<<2048, 256, 0, stream>>>(x, embedding, emb_hi, emb_lo);

  // xproj = embed @ w_ih^T + (b_ih + b_hh)
  gemm_split<<<32 * 16, 256, 0, stream>>>(emb_hi, emb_lo, wih_hi, wih_lo, xproj,
                                          b_ih, b_hh, 2048, 32);

  {
    void* args[] = {(void*)&xproj, (void*)&w_hh, (void*)&lstmf,
                    (void*)&lstm_hi, (void*)&lstm_lo};
    hipLaunchCooperativeKernel((void*)lstm_persistent, dim3(256), dim3(256), args, 0, stream);
  }

  // y = lstm_out @ dec_w^T + dec_b
  gemm_split<<<32 * 391, 256, 0, stream>>>(lstm_hi, lstm_lo, dw_hi, dw_lo,
                                           (float*)d_out, dec_b, (const float*)nullptr,
                                           50000, 32);
}

// Round 3
// 1367.191 us; speedup vs baseline: 1.4502x; 1.2595x over previous
//
#include <hip/hip_runtime.h>
#include <hip/hip_bf16.h>
#include <stdint.h>

// ---------- types / helpers ----------
typedef short bf16x8 __attribute__((ext_vector_type(8)));
typedef float f32x4 __attribute__((ext_vector_type(4)));

typedef const __attribute__((address_space(1))) unsigned int glob_u32;
typedef __attribute__((address_space(3))) unsigned int lds_u32;

__device__ __forceinline__ void gl_lds16(const void* g, void* s) {
  // 16B global->LDS direct copy; LDS dest = wave-uniform base + lane*16
  __builtin_amdgcn_global_load_lds((glob_u32*)g, (lds_u32*)s, 16, 0, 0);
}

__device__ __forceinline__ unsigned short f2bf(float f) {
  __hip_bfloat16 h = __float2bfloat16(f);
  return __builtin_bit_cast(unsigned short, h);
}
__device__ __forceinline__ float bf2f(unsigned short u) {
  __hip_bfloat16 h = __builtin_bit_cast(__hip_bfloat16, u);
  return __bfloat162float(h);
}

__device__ __forceinline__ float sigm_fast(float x) {
  float e = __expf(-x);
  return __builtin_amdgcn_rcpf(1.f + e);
}
__device__ __forceinline__ float tanh_fast(float x) {
  float e = __expf(2.f * x);                  // inf-safe: rcp(inf)=0 -> 1
  return 1.f - 2.f * __builtin_amdgcn_rcpf(e + 1.f);
}

// ---------- split fp32 -> bf16 hi/lo ----------
__global__ void split_hl(const float* __restrict__ src,
                         unsigned short* __restrict__ hi,
                         unsigned short* __restrict__ lo, int n4) {
  int i = blockIdx.x * blockDim.x + threadIdx.x;
  if (i >= n4) return;
  float4 v = reinterpret_cast<const float4*>(src)[i];
  ushort4 h, l;
  h.x = f2bf(v.x); l.x = f2bf(v.x - bf2f(h.x));
  h.y = f2bf(v.y); l.y = f2bf(v.y - bf2f(h.y));
  h.z = f2bf(v.z); l.z = f2bf(v.z - bf2f(h.z));
  h.w = f2bf(v.w); l.w = f2bf(v.w - bf2f(h.w));
  reinterpret_cast<ushort4*>(hi)[i] = h;
  reinterpret_cast<ushort4*>(lo)[i] = l;
}

// ---------- split fp32 -> bf16 hi only (decoder weights) ----------
__global__ void split_h(const float* __restrict__ src,
                        unsigned short* __restrict__ hi, int n4) {
  int i = blockIdx.x * blockDim.x + threadIdx.x;
  if (i >= n4) return;
  float4 v = reinterpret_cast<const float4*>(src)[i];
  ushort4 h;
  h.x = f2bf(v.x); h.y = f2bf(v.y); h.z = f2bf(v.z); h.w = f2bf(v.w);
  reinterpret_cast<ushort4*>(hi)[i] = h;
}

// ---------- embedding gather + split ----------
__global__ void gather_split(const int* __restrict__ x, const float* __restrict__ emb,
                             unsigned short* __restrict__ hi,
                             unsigned short* __restrict__ lo) {
  int i = blockIdx.x * 256 + threadIdx.x;  // [0, 4096*128)
  int m = i >> 7, k4 = i & 127;
  long row = x[m];
  float4 v = reinterpret_cast<const float4*>(emb + row * 512)[k4];
  ushort4 h, l;
  h.x = f2bf(v.x); l.x = f2bf(v.x - bf2f(h.x));
  h.y = f2bf(v.y); l.y = f2bf(v.y - bf2f(h.y));
  h.z = f2bf(v.z); l.z = f2bf(v.z - bf2f(h.z));
  h.w = f2bf(v.w); l.w = f2bf(v.w - bf2f(h.w));
  reinterpret_cast<ushort4*>(hi)[m * 128 + k4] = h;
  reinterpret_cast<ushort4*>(lo)[m * 128 + k4] = l;
}

// ---------- split-bf16 GEMM (3-product, for xproj): C = A@B^T + bias ----------
__global__ __launch_bounds__(256) void gemm_split(
    const unsigned short* __restrict__ Ahi, const unsigned short* __restrict__ Alo,
    const unsigned short* __restrict__ Bhi, const unsigned short* __restrict__ Blo,
    float* __restrict__ C, const float* __restrict__ bias1,
    const float* __restrict__ bias2, int N, int mtiles) {
  __shared__ unsigned short lds[4][128 * 64];  // Ahi, Alo, Bhi, Blo tiles
  int nwg = gridDim.x;
  int wid = (blockIdx.x & 7) * (nwg >> 3) + (blockIdx.x >> 3);
  int mt = wid % mtiles, nt = wid / mtiles;
  int m0 = mt * 128, n0 = nt * 128;
  int tid = threadIdx.x, l = tid & 63, w = tid >> 6;
  int wm = (w & 1) * 64, wn = (w >> 1) * 64;

  f32x4 acc[4][4];
#pragma unroll
  for (int a = 0; a < 4; ++a)
#pragma unroll
    for (int b = 0; b < 4; ++b) acc[a][b] = f32x4{0.f, 0.f, 0.f, 0.f};

  const unsigned short* srcs[4] = {Ahi, Alo, Bhi, Blo};

  for (int kc = 0; kc < 8; ++kc) {   // K=512 in chunks of 64
    __syncthreads();
#pragma unroll
    for (int tile = 0; tile < 4; ++tile) {
      const unsigned short* src = srcs[tile];
      int rbase = (tile < 2) ? m0 : n0;
#pragma unroll
      for (int i = 0; i < 4; ++i) {
        int G = (i * 4 + w) * 64 + l;
        int r = G >> 3, g = G & 7;
        int row = rbase + r;
        long gb = (long)row * 1024 + kc * 128 + ((g * 16) ^ ((r & 7) << 4));
        gl_lds16((const char*)src + gb, (char*)(&lds[tile][0]) + (i * 4 + w) * 1024);
      }
    }
    __syncthreads();

    const char* ldsb = (const char*)&lds[0][0];
#pragma unroll
    for (int ks = 0; ks < 2; ++ks) {
      bf16x8 ah[4], al[4], bh[4], bl[4];
      int biw = ks * 64 + ((l >> 4) * 16);
#pragma unroll
      for (int fm = 0; fm < 4; ++fm) {
        int row = wm + fm * 16 + (l & 15);
        int off = row * 128 + (biw ^ ((row & 7) << 4));
        ah[fm] = *reinterpret_cast<const bf16x8*>(ldsb + off);
        al[fm] = *reinterpret_cast<const bf16x8*>(ldsb + 16384 + off);
      }
#pragma unroll
      for (int fn = 0; fn < 4; ++fn) {
        int row = wn + fn * 16 + (l & 15);
        int off = row * 128 + (biw ^ ((row & 7) << 4));
        bh[fn] = *reinterpret_cast<const bf16x8*>(ldsb + 32768 + off);
        bl[fn] = *reinterpret_cast<const bf16x8*>(ldsb + 49152 + off);
      }
#pragma unroll
      for (int fm = 0; fm < 4; ++fm)
#pragma unroll
        for (int fn = 0; fn < 4; ++fn) {
          acc[fm][fn] = __builtin_amdgcn_mfma_f32_16x16x32_bf16(ah[fm], bh[fn], acc[fm][fn], 0, 0, 0);
          acc[fm][fn] = __builtin_amdgcn_mfma_f32_16x16x32_bf16(ah[fm], bl[fn], acc[fm][fn], 0, 0, 0);
          acc[fm][fn] = __builtin_amdgcn_mfma_f32_16x16x32_bf16(al[fm], bh[fn], acc[fm][fn], 0, 0, 0);
        }
    }
  }

#pragma unroll
  for (int fn = 0; fn < 4; ++fn) {
    int n = n0 + wn + fn * 16 + (l & 15);
    float bs = bias1[n];
    if (bias2) bs += bias2[n];
#pragma unroll
    for (int fm = 0; fm < 4; ++fm) {
      int mb = m0 + wm + fm * 16 + (l >> 4) * 4;
#pragma unroll
      for (int j = 0; j < 4; ++j)
        C[(long)(mb + j) * N + n] = acc[fm][fn][j] + bs;
    }
  }
}

// ---------- plain bf16 GEMM (single product, decoder): C = A@B^T + bias ----------
// M=4096, K=512. mt-partitioned per XCD: A slice (4 m-tiles, 524 KB) L2-resident.
__global__ __launch_bounds__(256) void gemm_plain(
    const unsigned short* __restrict__ Ahi, const unsigned short* __restrict__ Bhi,
    float* __restrict__ C, const float* __restrict__ bias1, int N) {
  __shared__ unsigned short lds[2][128 * 64];  // A, B tiles (32 KiB)
  int xcd = blockIdx.x & 7;
  int wid = blockIdx.x >> 3;        // 0..1563
  int mt = xcd * 4 + (wid & 3);     // each XCD owns 4 fixed m-tiles
  int nt = wid >> 2;                // 0..390
  int m0 = mt * 128, n0 = nt * 128;
  int tid = threadIdx.x, l = tid & 63, w = tid >> 6;
  int wm = (w & 1) * 64, wn = (w >> 1) * 64;

  f32x4 acc[4][4];
#pragma unroll
  for (int a = 0; a < 4; ++a)
#pragma unroll
    for (int b = 0; b < 4; ++b) acc[a][b] = f32x4{0.f, 0.f, 0.f, 0.f};

  const unsigned short* srcs[2] = {Ahi, Bhi};

  for (int kc = 0; kc < 8; ++kc) {
    __syncthreads();
#pragma unroll
    for (int tile = 0; tile < 2; ++tile) {
      const unsigned short* src = srcs[tile];
      int rbase = (tile < 1) ? m0 : n0;
#pragma unroll
      for (int i = 0; i < 4; ++i) {
        int G = (i * 4 + w) * 64 + l;
        int r = G >> 3, g = G & 7;
        int row = rbase + r;
        if (tile == 1 && row >= N) row = n0;  // clamp ragged N tile
        long gb = (long)row * 1024 + kc * 128 + ((g * 16) ^ ((r & 7) << 4));
        gl_lds16((const char*)src + gb, (char*)(&lds[tile][0]) + (i * 4 + w) * 1024);
      }
    }
    __syncthreads();

    const char* ldsb = (const char*)&lds[0][0];
#pragma unroll
    for (int ks = 0; ks < 2; ++ks) {
      bf16x8 ah[4], bh[4];
      int biw = ks * 64 + ((l >> 4) * 16);
#pragma unroll
      for (int fm = 0; fm < 4; ++fm) {
        int row = wm + fm * 16 + (l & 15);
        int off = row * 128 + (biw ^ ((row & 7) << 4));
        ah[fm] = *reinterpret_cast<const bf16x8*>(ldsb + off);
      }
#pragma unroll
      for (int fn = 0; fn < 4; ++fn) {
        int row = wn + fn * 16 + (l & 15);
        int off = row * 128 + (biw ^ ((row & 7) << 4));
        bh[fn] = *reinterpret_cast<const bf16x8*>(ldsb + 16384 + off);
      }
#pragma unroll
      for (int fm = 0; fm < 4; ++fm)
#pragma unroll
        for (int fn = 0; fn < 4; ++fn)
          acc[fm][fn] = __builtin_amdgcn_mfma_f32_16x16x32_bf16(ah[fm], bh[fn], acc[fm][fn], 0, 0, 0);
    }
  }

#pragma unroll
  for (int fn = 0; fn < 4; ++fn) {
    int n = n0 + wn + fn * 16 + (l & 15);
    if (n < N) {
      float bs = bias1[n];
#pragma unroll
      for (int fm = 0; fm < 4; ++fm) {
        int mb = m0 + wm + fm * 16 + (l >> 4) * 4;
#pragma unroll
        for (int j = 0; j < 4; ++j)
          C[(long)(mb + j) * N + n] = acc[fm][fn][j] + bs;
      }
    }
  }
}

// ---------- persistent LSTM ----------
__global__ __launch_bounds__(256, 1) void lstm_persistent(
    const float* __restrict__ xproj,   // [8][512][2048] (biases folded in)
    const float* __restrict__ whh,     // [2048][512]
    float* lstm_f32,                   // [8][512][512] sentinel-initialized
    unsigned short* __restrict__ lstm_hi) {
  int bid = blockIdx.x;
  int batch = bid & 7, slice = bid >> 3;
  int tid = threadIdx.x, l = tid & 63, w = tid >> 6;
  int g = l >> 4, e = l & 15;
  long R = (long)g * 512 + slice * 16 + e;  // gate row in [0,2048)

  __shared__ float h_s[512];
  __shared__ float part_s[2][4][64];  // double-buffered: one barrier per step

  // ---- load W slice and PIN it in VGPRs ----
  float wr[128];
  {
    const float4* wp = reinterpret_cast<const float4*>(whh + R * 512) + w * 32;
#pragma unroll
    for (int jj = 0; jj < 32; ++jj) {
      float4 v = wp[jj];
      wr[jj * 4 + 0] = v.x; wr[jj * 4 + 1] = v.y;
      wr[jj * 4 + 2] = v.z; wr[jj * 4 + 3] = v.w;
    }
  }
#pragma unroll
  for (int jj = 0; jj < 128; jj += 4)
    asm volatile("" : "+v"(wr[jj]), "+v"(wr[jj + 1]), "+v"(wr[jj + 2]), "+v"(wr[jj + 3]));

  const float* xbase = xproj + (long)batch * 512 * 2048 + g * 512 + slice * 16 + e;
  float* hrow_base = lstm_f32 + (long)batch * 512 * 512;
  float c_reg = 0.f;

  for (int t = 0; t < 512; ++t) {
    float xp = 0.f;
    if (w == 0) xp = xbase[(long)t * 2048];

    float a0 = 0.f, a1 = 0.f, a2 = 0.f, a3 = 0.f;
    if (t > 0) {
      // 2-deep pipelined sentinel poll: two loads in flight -> detect at ~latency/2
      const unsigned long long* src = reinterpret_cast<const unsigned long long*>(
          hrow_base + (long)(t - 1) * 512 + w * 128) + l;
      unsigned long long u = __hip_atomic_load(src, __ATOMIC_RELAXED, __HIP_MEMORY_SCOPE_AGENT);
      unsigned long long u2 = __hip_atomic_load(src, __ATOMIC_RELAXED, __HIP_MEMORY_SCOPE_AGENT);
      while ((unsigned)u == 0xFFFFFFFFu || (unsigned)(u >> 32) == 0xFFFFFFFFu) {
        u = u2;
        u2 = __hip_atomic_load(src, __ATOMIC_RELAXED, __HIP_MEMORY_SCOPE_AGENT);
      }
      float2 hf;
      hf.x = __builtin_bit_cast(float, (unsigned)u);
      hf.y = __builtin_bit_cast(float, (unsigned)(u >> 32));
      *reinterpret_cast<float2*>(&h_s[w * 128 + 2 * l]) = hf;
      asm volatile("s_waitcnt lgkmcnt(0)" ::: "memory");
      __builtin_amdgcn_sched_barrier(0);
#pragma unroll
      for (int jj = 0; jj < 32; ++jj) {
        float4 h4 = *reinterpret_cast<const float4*>(&h_s[w * 128 + jj * 4]);
        a0 = fmaf(wr[jj * 4 + 0], h4.x, a0);
        a1 = fmaf(wr[jj * 4 + 1], h4.y, a1);
        a2 = fmaf(wr[jj * 4 + 2], h4.z, a2);
        a3 = fmaf(wr[jj * 4 + 3], h4.w, a3);
      }
    }
    part_s[t & 1][w][l] = (a0 + a1) + (a2 + a3);
    __syncthreads();

    if (w == 0) {
      float sum = xp + part_s[t & 1][0][l] + part_s[t & 1][1][l] +
                  part_s[t & 1][2][l] + part_s[t & 1][3][l];
      float val = (g == 2) ? tanh_fast(sum) : sigm_fast(sum);
      float vf = __shfl(val, e + 16);   // f gate
      float vg = __shfl(val, e + 32);   // g gate
      float vo = __shfl(val, e + 48);   // o gate
      if (l < 16) {
        float c = vf * c_reg + val * vg;   // val = i for lanes 0..15
        c_reg = c;
        float h = vo * tanh_fast(c);
        long oidx = ((long)batch * 512 + t) * 512 + slice * 16 + l;
        __hip_atomic_store(reinterpret_cast<unsigned int*>(lstm_f32) + oidx,
                           __builtin_bit_cast(unsigned int, h),
                           __ATOMIC_RELAXED, __HIP_MEMORY_SCOPE_AGENT);
        lstm_hi[oidx] = f2bf(h);
      }
    }
    // no trailing barrier: part_s is double-buffered; h_s is wave-private
  }
}

// ---------- launch ----------
extern "C" void kernel_launch(void* const* d_in, const int* in_sizes, int n_in,
                              void* d_out, int out_size, void* d_ws, size_t ws_size,
                              hipStream_t stream) {
  const int*   x         = (const int*)d_in[0];
  const float* embedding = (const float*)d_in[2];
  const float* w_ih      = (const float*)d_in[3];
  const float* w_hh      = (const float*)d_in[4];
  const float* b_ih      = (const float*)d_in[5];
  const float* b_hh      = (const float*)d_in[6];
  const float* dec_w     = (const float*)d_in[7];
  const float* dec_b     = (const float*)d_in[8];

  char* ws = (char*)d_ws;
  float* xproj = (float*)ws;                      ws += (size_t)4096 * 2048 * 4;
  float* lstmf = (float*)ws;                      ws += (size_t)4096 * 512 * 4;
  unsigned short* lstm_hi = (unsigned short*)ws;  ws += (size_t)4096 * 512 * 2;
  unsigned short* emb_hi  = (unsigned short*)ws;  ws += (size_t)4096 * 512 * 2;
  unsigned short* emb_lo  = (unsigned short*)ws;  ws += (size_t)4096 * 512 * 2;
  unsigned short* wih_hi  = (unsigned short*)ws;  ws += (size_t)2048 * 512 * 2;
  unsigned short* wih_lo  = (unsigned short*)ws;  ws += (size_t)2048 * 512 * 2;
  unsigned short* dw_hi   = (unsigned short*)ws;  ws += (size_t)50000 * 512 * 2;

  // reset h sentinel (poll buffer) every call — determinism across replays
  hipMemsetAsync(lstmf, 0xFF, (size_t)4096 * 512 * 4, stream);

  split_hl<<<1024, 256, 0, stream>>>(w_ih, wih_hi, wih_lo, 2048 * 512 / 4);
  split_h<<<25000, 256, 0, stream>>>(dec_w, dw_hi, 50000 * 512 / 4);
  gather_split<<<2048, 256, 0, stream>>>(x, embedding, emb_hi, emb_lo);

  // xproj = embed @ w_ih^T + (b_ih + b_hh)   [3-product: feeds the recurrence]
  gemm_split<<<32 * 16, 256, 0, stream>>>(emb_hi, emb_lo, wih_hi, wih_lo, xproj,
                                          b_ih, b_hh, 2048, 32);

  {
    void* args[] = {(void*)&xproj, (void*)&w_hh, (void*)&lstmf, (void*)&lstm_hi};
    hipLaunchCooperativeKernel((void*)lstm_persistent, dim3(256), dim3(256), args, 0, stream);
  }

  // y = lstm_out @ dec_w^T + dec_b   [single bf16 product: abs error budget allows]
  gemm_plain<<<32 * 391, 256, 0, stream>>>(lstm_hi, dw_hi, (float*)d_out, dec_b, 50000);
}